// Round 1
// baseline (155.896 us; speedup 1.0000x reference)
//
#include <hip/hip_runtime.h>

typedef unsigned short u16;
typedef __bf16 bf16x8 __attribute__((ext_vector_type(8)));
typedef float f32x4 __attribute__((ext_vector_type(4)));

__device__ inline u16 f2bf(float f) {
    union { float f; unsigned u; } x; x.f = f;
    unsigned u = x.u;
    unsigned r = (u + 0x7fffu + ((u >> 16) & 1u)) >> 16;  // RNE
    return (u16)r;
}

__device__ inline float wave_reduce_sum(float v) {
    #pragma unroll
    for (int off = 32; off > 0; off >>= 1) v += __shfl_down(v, off);
    return v;
}

// One block per row: compute fp32 row L2-norm and convert row to bf16.
__global__ __launch_bounds__(256) void norm_convert_kernel(
        const float* __restrict__ in, u16* __restrict__ outbf,
        float* __restrict__ norms, int D) {
    const int row = blockIdx.x;
    const float4* r4 = reinterpret_cast<const float4*>(in + (size_t)row * D);
    ushort4* o4 = reinterpret_cast<ushort4*>(outbf + (size_t)row * D);
    float ss = 0.f;
    for (int c = threadIdx.x; c < (D >> 2); c += blockDim.x) {
        float4 v = r4[c];
        ss += v.x * v.x + v.y * v.y + v.z * v.z + v.w * v.w;
        ushort4 o;
        o.x = f2bf(v.x); o.y = f2bf(v.y); o.z = f2bf(v.z); o.w = f2bf(v.w);
        o4[c] = o;
    }
    __shared__ float red[4];
    float w = wave_reduce_sum(ss);
    if ((threadIdx.x & 63) == 0) red[threadIdx.x >> 6] = w;
    __syncthreads();
    if (threadIdx.x == 0)
        norms[row] = sqrtf(red[0] + red[1] + red[2] + red[3]);
}

// Upper-triangular-tile bf16 GEMM: C = Lbf * Rbf^T on 128x128 tiles with
// tile_i <= tile_j only. Epilogue: cos = dot / max(ln*rn, eps); sims = 10*cos;
// write S[i][j] and mirror S[j][i] (i<j), or S[i][i] on the diagonal.
__global__ __launch_bounds__(256) void gemm_sym_kernel(
        const u16* __restrict__ Lbf, const u16* __restrict__ Rbf,
        const float* __restrict__ ln, const float* __restrict__ rn,
        float* __restrict__ S, int B, int D, int TT) {
    // map linear block id -> (ti, tj) with ti <= tj
    int b = blockIdx.x;
    int ti = 0;
    while (b >= TT - ti) { b -= TT - ti; ti++; }
    const int tj = ti + b;

    const int brow = ti * 128;
    const int bcol = tj * 128;

    __shared__ __align__(16) u16 Ls[128][32];
    __shared__ __align__(16) u16 Rs[128][32];

    const int tid  = threadIdx.x;
    const int lane = tid & 63;
    const int wave = tid >> 6;       // 0..3
    const int wr   = wave >> 1;      // 0..1 : 64-row half
    const int wc   = wave & 1;       // 0..1 : 64-col half

    f32x4 acc[4][4] = {};

    const int fr = lane & 15;        // fragment row/col within 16
    const int kg = (lane >> 4) * 8;  // k-chunk start (0,8,16,24)

    for (int k0 = 0; k0 < D; k0 += 32) {
        // stage A and B tiles: 128 rows x 32 bf16 = 512 chunks of 16B each
        #pragma unroll
        for (int s = 0; s < 2; ++s) {
            int c   = tid + s * 256;        // 0..511
            int row = c >> 2;
            int kc  = (c & 3) * 8;
            *reinterpret_cast<uint4*>(&Ls[row][kc]) =
                *reinterpret_cast<const uint4*>(&Lbf[(size_t)(brow + row) * D + k0 + kc]);
            *reinterpret_cast<uint4*>(&Rs[row][kc]) =
                *reinterpret_cast<const uint4*>(&Rbf[(size_t)(bcol + row) * D + k0 + kc]);
        }
        __syncthreads();

        bf16x8 af[4], bfr[4];
        #pragma unroll
        for (int m = 0; m < 4; ++m)
            af[m] = *reinterpret_cast<const bf16x8*>(&Ls[wr * 64 + m * 16 + fr][kg]);
        #pragma unroll
        for (int n = 0; n < 4; ++n)
            bfr[n] = *reinterpret_cast<const bf16x8*>(&Rs[wc * 64 + n * 16 + fr][kg]);

        #pragma unroll
        for (int m = 0; m < 4; ++m)
            #pragma unroll
            for (int n = 0; n < 4; ++n)
                acc[m][n] = __builtin_amdgcn_mfma_f32_16x16x32_bf16(
                    af[m], bfr[n], acc[m][n], 0, 0, 0);
        __syncthreads();
    }

    // epilogue: C/D layout col = lane&15, row = (lane>>4)*4 + r
    const int fcol  = lane & 15;
    const int frow0 = (lane >> 4) * 4;
    #pragma unroll
    for (int m = 0; m < 4; ++m) {
        const int ibase = brow + wr * 64 + m * 16 + frow0;
        #pragma unroll
        for (int n = 0; n < 4; ++n) {
            const int j = bcol + wc * 64 + n * 16 + fcol;
            const float rnj = rn[j];
            #pragma unroll
            for (int r = 0; r < 4; ++r) {
                const int i = ibase + r;
                if (i > j) continue;
                const float denom = fmaxf(ln[i] * rnj, 1e-8f);
                const float v = acc[m][n][r] * 10.0f / denom;
                S[(size_t)i * B + j] = v;
                if (i < j) S[(size_t)j * B + i] = v;
            }
        }
    }
}

// Per-row: loss_i = log(sum_j exp(S[i,j])) - S[i,i]   (values bounded by 10,
// so no max-subtraction needed; sum <= B*e^10 ~ 9e7, fp32-safe)
__global__ __launch_bounds__(256) void row_lse_kernel(
        const float* __restrict__ S, float* __restrict__ row_loss, int B) {
    const int i = blockIdx.x;
    const float4* row4 = reinterpret_cast<const float4*>(S + (size_t)i * B);
    float s = 0.f;
    for (int c = threadIdx.x; c < (B >> 2); c += blockDim.x) {
        float4 v = row4[c];
        s += __expf(v.x) + __expf(v.y) + __expf(v.z) + __expf(v.w);
    }
    __shared__ float red[4];
    float w = wave_reduce_sum(s);
    if ((threadIdx.x & 63) == 0) red[threadIdx.x >> 6] = w;
    __syncthreads();
    if (threadIdx.x == 0) {
        float tot = red[0] + red[1] + red[2] + red[3];
        row_loss[i] = logf(tot) - S[(size_t)i * B + i];
    }
}

__global__ __launch_bounds__(256) void final_reduce_kernel(
        const float* __restrict__ rl, float* __restrict__ out, int B) {
    float s = 0.f;
    for (int c = threadIdx.x; c < B; c += blockDim.x) s += rl[c];
    __shared__ float red[4];
    float w = wave_reduce_sum(s);
    if ((threadIdx.x & 63) == 0) red[threadIdx.x >> 6] = w;
    __syncthreads();
    if (threadIdx.x == 0) out[0] = (red[0] + red[1] + red[2] + red[3]) / (float)B;
}

extern "C" void kernel_launch(void* const* d_in, const int* in_sizes, int n_in,
                              void* d_out, int out_size, void* d_ws, size_t ws_size,
                              hipStream_t stream) {
    const float* L = (const float*)d_in[0];
    const float* R = (const float*)d_in[1];
    const int D = 1024;
    const int B = in_sizes[0] / D;   // 4096

    char* ws = (char*)d_ws;
    size_t o = 0;
    u16* Lbf = (u16*)(ws + o);       o += (size_t)B * D * sizeof(u16);
    u16* Rbf = (u16*)(ws + o);       o += (size_t)B * D * sizeof(u16);
    float* ln = (float*)(ws + o);    o += (size_t)B * sizeof(float);
    float* rn = (float*)(ws + o);    o += (size_t)B * sizeof(float);
    float* rl = (float*)(ws + o);    o += (size_t)B * sizeof(float);
    float* S  = (float*)(ws + o);    o += (size_t)B * B * sizeof(float);

    norm_convert_kernel<<<B, 256, 0, stream>>>(L, Lbf, ln, D);
    norm_convert_kernel<<<B, 256, 0, stream>>>(R, Rbf, rn, D);

    const int TT = B / 128;                   // 32 tiles per dim
    const int nblocks = TT * (TT + 1) / 2;    // 528 upper-triangular tiles
    gemm_sym_kernel<<<nblocks, 256, 0, stream>>>(Lbf, Rbf, ln, rn, S, B, D, TT);

    row_lse_kernel<<<B, 256, 0, stream>>>(S, rl, B);
    final_reduce_kernel<<<1, 256, 0, stream>>>(rl, (float*)d_out, B);
}

// Round 3
// 141.315 us; speedup vs baseline: 1.1032x; 1.1032x over previous
//
#include <hip/hip_runtime.h>

typedef unsigned short u16;
typedef __bf16 bf16x8 __attribute__((ext_vector_type(8)));
typedef float f32x4 __attribute__((ext_vector_type(4)));

#define B_DIM 4096
#define D_DIM 1024
#define TT    32   // 128-wide tiles per dim

#define GLOAD_LDS16(g, l)                                            \
    __builtin_amdgcn_global_load_lds(                                \
        (const __attribute__((address_space(1))) void*)(g),          \
        (__attribute__((address_space(3))) void*)(l), 16, 0, 0)

__device__ inline u16 f2bf(float f) {
    union { float f; unsigned u; } x; x.f = f;
    unsigned u = x.u;
    return (u16)((u + 0x7fffu + ((u >> 16) & 1u)) >> 16);  // RNE
}

__device__ inline float wave_reduce_sum(float v) {
    #pragma unroll
    for (int off = 32; off > 0; off >>= 1) v += __shfl_down(v, off);
    return v;
}

// grid = 2*B : block b < B handles L row b; else R row b-B.
// fp32 row L2-norm (exact, matches reference) + bf16 conversion.
__global__ __launch_bounds__(256) void norm_convert_kernel(
        const float* __restrict__ L, const float* __restrict__ R,
        u16* __restrict__ Lbf, u16* __restrict__ Rbf,
        float* __restrict__ ln, float* __restrict__ rn) {
    int b = blockIdx.x;
    const float* in; u16* outb; float* nout; int row;
    if (b < B_DIM) { in = L; outb = Lbf; nout = ln; row = b; }
    else           { in = R; outb = Rbf; nout = rn; row = b - B_DIM; }

    const float4* r4 = reinterpret_cast<const float4*>(in + (size_t)row * D_DIM);
    ushort4* o4 = reinterpret_cast<ushort4*>(outb + (size_t)row * D_DIM);
    float ss = 0.f;
    for (int c = threadIdx.x; c < (D_DIM >> 2); c += blockDim.x) {
        float4 v = r4[c];
        ss += v.x * v.x + v.y * v.y + v.z * v.z + v.w * v.w;
        ushort4 o;
        o.x = f2bf(v.x); o.y = f2bf(v.y); o.z = f2bf(v.z); o.w = f2bf(v.w);
        o4[c] = o;
    }
    __shared__ float red[4];
    float w = wave_reduce_sum(ss);
    if ((threadIdx.x & 63) == 0) red[threadIdx.x >> 6] = w;
    __syncthreads();
    if (threadIdx.x == 0)
        nout[row] = sqrtf(red[0] + red[1] + red[2] + red[3]);
}

// Upper-triangular-tile bf16 MFMA GEMM with fused softmax-denominator
// epilogue. Never materializes S: each block atomically accumulates
// sum_j exp(S[i,j]) into rowsum[] (rows for i<=j, mirrored cols for i<j)
// and writes diag[i] = S[i,i].
__global__ __launch_bounds__(256) void gemm_fused_kernel(
        const u16* __restrict__ Lbf, const u16* __restrict__ Rbf,
        const float* __restrict__ ln, const float* __restrict__ rn,
        float* __restrict__ rowsum, float* __restrict__ diag) {
    __shared__ __align__(16) u16 Ls[128 * 64];   // 128 rows x 64 bf16 (swizzled)
    __shared__ __align__(16) u16 Rs[128 * 64];

    // linear block id -> (ti, tj), ti <= tj
    int b = (int)blockIdx.x;
    int ti = 0;
    while (b >= TT - ti) { b -= TT - ti; ++ti; }
    const int tj = ti + b;
    const int brow = ti * 128;
    const int bcol = tj * 128;
    const bool diagblk = (ti == tj);

    const int tid  = threadIdx.x;
    const int lane = tid & 63;
    const int wave = tid >> 6;   // 0..3
    const int wr   = wave >> 1;  // row half
    const int wc   = wave & 1;   // col half
    const int fr   = lane & 15;

    // --- staging addresses (pre-swizzled global source; linear LDS dest) ---
    // Each global_load_lds: 64 lanes x 16B = 1KB = 8 rows x 128B.
    // LDS slot (row, cslot) holds logical chunk = cslot ^ (row&7).
    const int l8 = lane >> 3;   // row within 8-row group
    const int c8 = lane & 7;    // 16B chunk slot within row
    size_t gA[4], gB[4];
    u16 *lA[4], *lB[4];
    #pragma unroll
    for (int s = 0; s < 4; ++s) {
        int row = (wave * 4 + s) * 8 + l8;
        int chunk = c8 ^ (row & 7);
        gA[s] = (size_t)(brow + row) * D_DIM + chunk * 8;
        gB[s] = (size_t)(bcol + row) * D_DIM + chunk * 8;
        lA[s] = Ls + (wave * 4 + s) * 512;   // wave-uniform base
        lB[s] = Rs + (wave * 4 + s) * 512;
    }

    f32x4 acc[4][4] = {};

    for (int k0 = 0; k0 < D_DIM; k0 += 64) {
        #pragma unroll
        for (int s = 0; s < 4; ++s) {
            GLOAD_LDS16(Lbf + gA[s] + k0, lA[s]);
            GLOAD_LDS16(Rbf + gB[s] + k0, lB[s]);
        }
        __syncthreads();

        #pragma unroll
        for (int kk = 0; kk < 2; ++kk) {
            bf16x8 af[4], bfr[4];
            #pragma unroll
            for (int m = 0; m < 4; ++m) {
                int row = wr * 64 + m * 16 + fr;
                int cs = ((kk << 2) | (lane >> 4)) ^ (row & 7);
                af[m] = *reinterpret_cast<const bf16x8*>(&Ls[row * 64 + cs * 8]);
            }
            #pragma unroll
            for (int n = 0; n < 4; ++n) {
                int row = wc * 64 + n * 16 + fr;
                int cs = ((kk << 2) | (lane >> 4)) ^ (row & 7);
                bfr[n] = *reinterpret_cast<const bf16x8*>(&Rs[row * 64 + cs * 8]);
            }
            #pragma unroll
            for (int m = 0; m < 4; ++m)
                #pragma unroll
                for (int n = 0; n < 4; ++n)
                    acc[m][n] = __builtin_amdgcn_mfma_f32_16x16x32_bf16(
                        af[m], bfr[n], acc[m][n], 0, 0, 0);
        }
        __syncthreads();
    }

    // --- fused epilogue: cos -> sims -> exp -> row/col partial sums ---
    // C/D layout: col = lane&15, row = (lane>>4)*4 + r
    const int fcol  = lane & 15;
    const int frow0 = (lane >> 4) * 4;

    float rnj[4];
    #pragma unroll
    for (int n = 0; n < 4; ++n)
        rnj[n] = rn[bcol + wc * 64 + n * 16 + fcol];

    float colacc[4] = {0.f, 0.f, 0.f, 0.f};

    #pragma unroll
    for (int m = 0; m < 4; ++m) {
        #pragma unroll
        for (int r = 0; r < 4; ++r) {
            const int i = brow + wr * 64 + m * 16 + frow0 + r;
            const float lni = ln[i];
            float rowacc = 0.f;
            #pragma unroll
            for (int n = 0; n < 4; ++n) {
                const int j = bcol + wc * 64 + n * 16 + fcol;
                const float denom = fmaxf(lni * rnj[n], 1e-8f);
                const float v = acc[m][n][r] * 10.0f / denom;
                if (diagblk && i == j) diag[i] = v;
                const float e = __expf(v);
                if (i <= j) rowacc += e;
                if (i < j)  colacc[n] += e;
            }
            // reduce across the 16 fcol lanes (low 4 lane bits)
            rowacc += __shfl_xor(rowacc, 1);
            rowacc += __shfl_xor(rowacc, 2);
            rowacc += __shfl_xor(rowacc, 4);
            rowacc += __shfl_xor(rowacc, 8);
            if (fcol == 0) atomicAdd(&rowsum[i], rowacc);
        }
    }
    #pragma unroll
    for (int n = 0; n < 4; ++n) {
        float c = colacc[n];
        c += __shfl_xor(c, 16);
        c += __shfl_xor(c, 32);
        if (lane < 16) {
            const int j = bcol + wc * 64 + n * 16 + fcol;
            atomicAdd(&rowsum[j], c);
        }
    }
}

// loss = mean_i( log(rowsum[i]) - diag[i] )
__global__ __launch_bounds__(256) void final_loss_kernel(
        const float* __restrict__ rowsum, const float* __restrict__ diag,
        float* __restrict__ out) {
    float s = 0.f;
    for (int i = threadIdx.x; i < B_DIM; i += 256)
        s += logf(rowsum[i]) - diag[i];
    __shared__ float red[4];
    float w = wave_reduce_sum(s);
    if ((threadIdx.x & 63) == 0) red[threadIdx.x >> 6] = w;
    __syncthreads();
    if (threadIdx.x == 0)
        out[0] = (red[0] + red[1] + red[2] + red[3]) / (float)B_DIM;
}

extern "C" void kernel_launch(void* const* d_in, const int* in_sizes, int n_in,
                              void* d_out, int out_size, void* d_ws, size_t ws_size,
                              hipStream_t stream) {
    const float* L = (const float*)d_in[0];
    const float* R = (const float*)d_in[1];

    char* ws = (char*)d_ws;
    size_t o = 0;
    u16* Lbf   = (u16*)(ws + o);   o += (size_t)B_DIM * D_DIM * sizeof(u16);
    u16* Rbf   = (u16*)(ws + o);   o += (size_t)B_DIM * D_DIM * sizeof(u16);
    float* ln  = (float*)(ws + o); o += (size_t)B_DIM * sizeof(float);
    float* rn  = (float*)(ws + o); o += (size_t)B_DIM * sizeof(float);
    float* rs  = (float*)(ws + o); o += (size_t)B_DIM * sizeof(float);
    float* dg  = (float*)(ws + o); o += (size_t)B_DIM * sizeof(float);

    hipMemsetAsync(rs, 0, B_DIM * sizeof(float), stream);

    norm_convert_kernel<<<2 * B_DIM, 256, 0, stream>>>(L, R, Lbf, Rbf, ln, rn);

    const int nblocks = TT * (TT + 1) / 2;   // 528 upper-triangular tiles
    gemm_fused_kernel<<<nblocks, 256, 0, stream>>>(Lbf, Rbf, ln, rn, rs, dg);

    final_loss_kernel<<<1, 256, 0, stream>>>(rs, dg, (float*)d_out);
}

// Round 7
// 138.533 us; speedup vs baseline: 1.1253x; 1.0201x over previous
//
#include <hip/hip_runtime.h>

typedef unsigned short u16;
typedef __bf16 bf16x8 __attribute__((ext_vector_type(8)));
typedef float f32x4 __attribute__((ext_vector_type(4)));

#define B_DIM 4096
#define D_DIM 1024
#define TT    32   // 128-wide tiles per dim

#define GLOAD_LDS16(g, l)                                            \
    __builtin_amdgcn_global_load_lds(                                \
        (const __attribute__((address_space(1))) void*)(g),          \
        (__attribute__((address_space(3))) void*)(l), 16, 0, 0)

__device__ inline u16 f2bf(float f) {
    union { float f; unsigned u; } x; x.f = f;
    unsigned u = x.u;
    return (u16)((u + 0x7fffu + ((u >> 16) & 1u)) >> 16);  // RNE
}

__device__ inline float wave_reduce_sum(float v) {
    #pragma unroll
    for (int off = 32; off > 0; off >>= 1) v += __shfl_down(v, off);
    return v;
}

// 1 wave per row, 4 rows per block; grid = 2*B/4.
// fp32 row L2-norm (exact, matches reference) + bf16 conversion.
__global__ __launch_bounds__(256) void norm_convert_kernel(
        const float* __restrict__ L, const float* __restrict__ R,
        u16* __restrict__ Lbf, u16* __restrict__ Rbf,
        float* __restrict__ ln, float* __restrict__ rn) {
    const int wave = threadIdx.x >> 6;
    const int lane = threadIdx.x & 63;
    int g = blockIdx.x * 4 + wave;          // 0 .. 2*B-1
    const float* in; u16* outb; float* nout; int row;
    if (g < B_DIM) { in = L; outb = Lbf; nout = ln; row = g; }
    else           { in = R; outb = Rbf; nout = rn; row = g - B_DIM; }

    const float4* r4 = reinterpret_cast<const float4*>(in + (size_t)row * D_DIM);
    ushort4* o4 = reinterpret_cast<ushort4*>(outb + (size_t)row * D_DIM);
    float ss = 0.f;
    #pragma unroll
    for (int c = 0; c < 4; ++c) {
        float4 v = r4[lane + 64 * c];
        ss += v.x * v.x + v.y * v.y + v.z * v.z + v.w * v.w;
        ushort4 o;
        o.x = f2bf(v.x); o.y = f2bf(v.y); o.z = f2bf(v.z); o.w = f2bf(v.w);
        o4[lane + 64 * c] = o;
    }
    #pragma unroll
    for (int off = 32; off > 0; off >>= 1) ss += __shfl_xor(ss, off);
    if (lane == 0) nout[row] = sqrtf(ss);
}

// Upper-triangular-tile bf16 MFMA GEMM, 2-phase double-buffered K-loop,
// fused softmax-denominator epilogue (never materializes S).
__global__ __launch_bounds__(256) void gemm_fused_kernel(
        const u16* __restrict__ Lbf, const u16* __restrict__ Rbf,
        const float* __restrict__ ln, const float* __restrict__ rn,
        float* __restrict__ rowsum, float* __restrict__ diag) {
    // 2 buffers x 128 rows x 64 bf16 each for A and B = 64 KiB total
    __shared__ __align__(16) u16 Ls[2][128 * 64];
    __shared__ __align__(16) u16 Rs[2][128 * 64];

    // linear block id -> (ti, tj), ti <= tj
    int b = (int)blockIdx.x;
    int ti = 0;
    while (b >= TT - ti) { b -= TT - ti; ++ti; }
    const int tj = ti + b;
    const int brow = ti * 128;
    const int bcol = tj * 128;
    const bool diagblk = (ti == tj);

    const int tid  = threadIdx.x;
    const int lane = tid & 63;
    const int wave = tid >> 6;   // 0..3
    const int wr   = wave >> 1;  // row half
    const int wc   = wave & 1;   // col half
    const int fr   = lane & 15;

    // staging: per wave 4 gloads for A + 4 for B; each gload = 64 lanes x 16B
    // = 8 rows x 128B. Global source pre-swizzled (chunk ^ row&7); LDS linear.
    const int l8 = lane >> 3;
    const int c8 = lane & 7;
    size_t gA[4], gB[4];
    int ldsOff[4];
    #pragma unroll
    for (int s = 0; s < 4; ++s) {
        int row = (wave * 4 + s) * 8 + l8;
        int chunk = c8 ^ (row & 7);
        gA[s] = (size_t)(brow + row) * D_DIM + chunk * 8;
        gB[s] = (size_t)(bcol + row) * D_DIM + chunk * 8;
        ldsOff[s] = (wave * 4 + s) * 512;   // wave-uniform
    }

#define STAGE(buf, k0)                                               \
    do {                                                             \
        _Pragma("unroll")                                            \
        for (int s = 0; s < 4; ++s) {                                \
            GLOAD_LDS16(Lbf + gA[s] + (k0), &Ls[buf][ldsOff[s]]);    \
            GLOAD_LDS16(Rbf + gB[s] + (k0), &Rs[buf][ldsOff[s]]);    \
        }                                                            \
    } while (0)

    f32x4 acc[4][4] = {};

#define COMPUTE(buf)                                                  \
    do {                                                              \
        _Pragma("unroll")                                             \
        for (int kk = 0; kk < 2; ++kk) {                              \
            bf16x8 af[4], bfr[4];                                     \
            _Pragma("unroll")                                         \
            for (int m = 0; m < 4; ++m) {                             \
                int row = wr * 64 + m * 16 + fr;                      \
                int cs = ((kk << 2) | (lane >> 4)) ^ (row & 7);       \
                af[m] = *reinterpret_cast<const bf16x8*>(             \
                    &Ls[buf][row * 64 + cs * 8]);                     \
            }                                                         \
            _Pragma("unroll")                                         \
            for (int n = 0; n < 4; ++n) {                             \
                int row = wc * 64 + n * 16 + fr;                      \
                int cs = ((kk << 2) | (lane >> 4)) ^ (row & 7);       \
                bfr[n] = *reinterpret_cast<const bf16x8*>(            \
                    &Rs[buf][row * 64 + cs * 8]);                     \
            }                                                         \
            _Pragma("unroll")                                         \
            for (int m = 0; m < 4; ++m)                               \
                _Pragma("unroll")                                     \
                for (int n = 0; n < 4; ++n)                           \
                    acc[m][n] = __builtin_amdgcn_mfma_f32_16x16x32_bf16( \
                        af[m], bfr[n], acc[m][n], 0, 0, 0);           \
        }                                                             \
    } while (0)

    // prologue: stage K-tile 0 into buf 0
    STAGE(0, 0);
    __syncthreads();                     // vmcnt(0) drain + barrier

    int cur = 0;
    for (int t = 0; t < 15; ++t) {
        STAGE(cur ^ 1, (t + 1) * 64);    // prefetch next tile first
        COMPUTE(cur);                    // MFMA hides the load latency
        __syncthreads();                 // drain prefetch, release buffers
        cur ^= 1;
    }
    COMPUTE(cur);                        // last tile, no prefetch

    // --- fused epilogue: cos -> sims -> exp -> row/col partial sums ---
    // C/D layout: col = lane&15, row = (lane>>4)*4 + r
    const int fcol  = lane & 15;
    const int frow0 = (lane >> 4) * 4;

    float rnj[4];
    #pragma unroll
    for (int n = 0; n < 4; ++n)
        rnj[n] = rn[bcol + wc * 64 + n * 16 + fcol];

    float colacc[4] = {0.f, 0.f, 0.f, 0.f};

    #pragma unroll
    for (int m = 0; m < 4; ++m) {
        #pragma unroll
        for (int r = 0; r < 4; ++r) {
            const int i = brow + wr * 64 + m * 16 + frow0 + r;
            const float lni = ln[i];
            float rowacc = 0.f;
            #pragma unroll
            for (int n = 0; n < 4; ++n) {
                const int j = bcol + wc * 64 + n * 16 + fcol;
                const float denom = fmaxf(lni * rnj[n], 1e-8f);
                const float v = acc[m][n][r] * 10.0f / denom;
                if (diagblk && i == j) diag[i] = v;
                const float e = __expf(v);
                if (i <= j) rowacc += e;
                if (i < j)  colacc[n] += e;
            }
            rowacc += __shfl_xor(rowacc, 1);
            rowacc += __shfl_xor(rowacc, 2);
            rowacc += __shfl_xor(rowacc, 4);
            rowacc += __shfl_xor(rowacc, 8);
            if (fcol == 0) atomicAdd(&rowsum[i], rowacc);
        }
    }
    #pragma unroll
    for (int n = 0; n < 4; ++n) {
        float c = colacc[n];
        c += __shfl_xor(c, 16);
        c += __shfl_xor(c, 32);
        if (lane < 16) {
            const int j = bcol + wc * 64 + n * 16 + fcol;
            atomicAdd(&rowsum[j], c);
        }
    }
#undef STAGE
#undef COMPUTE
}

// loss = mean_i( log(rowsum[i]) - diag[i] )
__global__ __launch_bounds__(1024) void final_loss_kernel(
        const float* __restrict__ rowsum, const float* __restrict__ diag,
        float* __restrict__ out) {
    float s = 0.f;
    for (int i = threadIdx.x; i < B_DIM; i += 1024)
        s += logf(rowsum[i]) - diag[i];
    __shared__ float red[16];
    float w = wave_reduce_sum(s);
    if ((threadIdx.x & 63) == 0) red[threadIdx.x >> 6] = w;
    __syncthreads();
    if (threadIdx.x == 0) {
        float tot = 0.f;
        #pragma unroll
        for (int k = 0; k < 16; ++k) tot += red[k];
        out[0] = tot / (float)B_DIM;
    }
}

extern "C" void kernel_launch(void* const* d_in, const int* in_sizes, int n_in,
                              void* d_out, int out_size, void* d_ws, size_t ws_size,
                              hipStream_t stream) {
    const float* L = (const float*)d_in[0];
    const float* R = (const float*)d_in[1];

    char* ws = (char*)d_ws;
    size_t o = 0;
    u16* Lbf   = (u16*)(ws + o);   o += (size_t)B_DIM * D_DIM * sizeof(u16);
    u16* Rbf   = (u16*)(ws + o);   o += (size_t)B_DIM * D_DIM * sizeof(u16);
    float* ln  = (float*)(ws + o); o += (size_t)B_DIM * sizeof(float);
    float* rn  = (float*)(ws + o); o += (size_t)B_DIM * sizeof(float);
    float* rs  = (float*)(ws + o); o += (size_t)B_DIM * sizeof(float);
    float* dg  = (float*)(ws + o); o += (size_t)B_DIM * sizeof(float);

    hipMemsetAsync(rs, 0, B_DIM * sizeof(float), stream);

    norm_convert_kernel<<<2 * B_DIM / 4, 256, 0, stream>>>(L, R, Lbf, Rbf, ln, rn);

    const int nblocks = TT * (TT + 1) / 2;   // 528 upper-triangular tiles
    gemm_fused_kernel<<<nblocks, 256, 0, stream>>>(Lbf, Rbf, ln, rn, rs, dg);

    final_loss_kernel<<<1, 1024, 0, stream>>>(rs, dg, (float*)d_out);
}

// Round 8
// 131.738 us; speedup vs baseline: 1.1834x; 1.0516x over previous
//
#include <hip/hip_runtime.h>

typedef unsigned short u16;
typedef __bf16 bf16x8 __attribute__((ext_vector_type(8)));
typedef float f32x4 __attribute__((ext_vector_type(4)));

#define B_DIM 4096
#define D_DIM 1024
#define TT    32   // 128-wide tiles per dim
#define NT    16   // K-tiles (1024 / 64)

#define GLOAD_LDS16(g, l)                                            \
    __builtin_amdgcn_global_load_lds(                                \
        (const __attribute__((address_space(1))) void*)(g),          \
        (__attribute__((address_space(3))) void*)(l), 16, 0, 0)

__device__ inline u16 f2bf(float f) {
    union { float f; unsigned u; } x; x.f = f;
    unsigned u = x.u;
    return (u16)((u + 0x7fffu + ((u >> 16) & 1u)) >> 16);  // RNE
}

__device__ inline float wave_reduce_sum(float v) {
    #pragma unroll
    for (int off = 32; off > 0; off >>= 1) v += __shfl_down(v, off);
    return v;
}

// 1 wave per row, 4 rows per block; grid = 2*B/4.
// fp32 row L2-norm (exact, matches reference) + bf16 conversion.
// Block 0 additionally zeroes rowsum (replaces hipMemsetAsync dispatch).
__global__ __launch_bounds__(256) void norm_convert_kernel(
        const float* __restrict__ L, const float* __restrict__ R,
        u16* __restrict__ Lbf, u16* __restrict__ Rbf,
        float* __restrict__ ln, float* __restrict__ rn,
        float* __restrict__ rowsum) {
    if (blockIdx.x == 0) {
        #pragma unroll
        for (int i = 0; i < B_DIM / 256; ++i)
            rowsum[threadIdx.x + i * 256] = 0.f;
    }
    const int wave = threadIdx.x >> 6;
    const int lane = threadIdx.x & 63;
    int g = blockIdx.x * 4 + wave;          // 0 .. 2*B-1
    const float* in; u16* outb; float* nout; int row;
    if (g < B_DIM) { in = L; outb = Lbf; nout = ln; row = g; }
    else           { in = R; outb = Rbf; nout = rn; row = g - B_DIM; }

    const float4* r4 = reinterpret_cast<const float4*>(in + (size_t)row * D_DIM);
    ushort4* o4 = reinterpret_cast<ushort4*>(outb + (size_t)row * D_DIM);
    float ss = 0.f;
    #pragma unroll
    for (int c = 0; c < 4; ++c) {
        float4 v = r4[lane + 64 * c];
        ss += v.x * v.x + v.y * v.y + v.z * v.z + v.w * v.w;
        ushort4 o;
        o.x = f2bf(v.x); o.y = f2bf(v.y); o.z = f2bf(v.z); o.w = f2bf(v.w);
        o4[lane + 64 * c] = o;
    }
    #pragma unroll
    for (int off = 32; off > 0; off >>= 1) ss += __shfl_xor(ss, off);
    if (lane == 0) nout[row] = sqrtf(ss);
}

// Upper-triangular-tile bf16 MFMA GEMM with counted-vmcnt double-buffered
// K-loop (prefetch stays in flight ACROSS the barrier — T4) and fused
// softmax-denominator epilogue (never materializes S).
__global__ __launch_bounds__(256) void gemm_fused_kernel(
        const u16* __restrict__ Lbf, const u16* __restrict__ Rbf,
        const float* __restrict__ ln, const float* __restrict__ rn,
        float* __restrict__ rowsum, float* __restrict__ diag) {
    // 2 buffers x 128 rows x 64 bf16 each for A and B = 64 KiB total
    __shared__ __align__(16) u16 Ls[2][128 * 64];
    __shared__ __align__(16) u16 Rs[2][128 * 64];

    // XCD-aware swizzle: 528 blocks = 8 XCDs x 66 -> bijective chunking so
    // each XCD owns 66 consecutive upper-tri tiles (A-panel reuse in its L2).
    int bid = (int)blockIdx.x;
    int swz = (bid & 7) * 66 + (bid >> 3);
    // linear swz -> (ti, tj), ti <= tj
    int b = swz;
    int ti = 0;
    while (b >= TT - ti) { b -= TT - ti; ++ti; }
    const int tj = ti + b;
    const int brow = ti * 128;
    const int bcol = tj * 128;
    const bool diagblk = (ti == tj);

    const int tid  = threadIdx.x;
    const int lane = tid & 63;
    const int wave = tid >> 6;   // 0..3
    const int wr   = wave >> 1;  // row half
    const int wc   = wave & 1;   // col half
    const int fr   = lane & 15;

    // staging: per wave 4 gloads for A + 4 for B; each gload = 64 lanes x 16B
    // = 8 rows x 128B. Global source pre-swizzled (chunk ^ row&7); LDS linear.
    const int l8 = lane >> 3;
    const int c8 = lane & 7;
    size_t gA[4], gB[4];
    int ldsOff[4];
    #pragma unroll
    for (int s = 0; s < 4; ++s) {
        int row = (wave * 4 + s) * 8 + l8;
        int chunk = c8 ^ (row & 7);
        gA[s] = (size_t)(brow + row) * D_DIM + chunk * 8;
        gB[s] = (size_t)(bcol + row) * D_DIM + chunk * 8;
        ldsOff[s] = (wave * 4 + s) * 512;   // wave-uniform
    }

#define STAGE(buf, k0)                                               \
    do {                                                             \
        _Pragma("unroll")                                            \
        for (int s = 0; s < 4; ++s) {                                \
            GLOAD_LDS16(Lbf + gA[s] + (k0), &Ls[buf][ldsOff[s]]);    \
            GLOAD_LDS16(Rbf + gB[s] + (k0), &Rs[buf][ldsOff[s]]);    \
        }                                                            \
    } while (0)

    f32x4 acc[4][4] = {};

#define COMPUTE(buf)                                                  \
    do {                                                              \
        _Pragma("unroll")                                             \
        for (int kk = 0; kk < 2; ++kk) {                              \
            bf16x8 af[4], bfr[4];                                     \
            _Pragma("unroll")                                         \
            for (int m = 0; m < 4; ++m) {                             \
                int row = wr * 64 + m * 16 + fr;                      \
                int cs = ((kk << 2) | (lane >> 4)) ^ (row & 7);       \
                af[m] = *reinterpret_cast<const bf16x8*>(             \
                    &Ls[buf][row * 64 + cs * 8]);                     \
            }                                                         \
            _Pragma("unroll")                                         \
            for (int n = 0; n < 4; ++n) {                             \
                int row = wc * 64 + n * 16 + fr;                      \
                int cs = ((kk << 2) | (lane >> 4)) ^ (row & 7);       \
                bfr[n] = *reinterpret_cast<const bf16x8*>(            \
                    &Rs[buf][row * 64 + cs * 8]);                     \
            }                                                         \
            _Pragma("unroll")                                         \
            for (int m = 0; m < 4; ++m)                               \
                _Pragma("unroll")                                     \
                for (int n = 0; n < 4; ++n)                           \
                    acc[m][n] = __builtin_amdgcn_mfma_f32_16x16x32_bf16( \
                        af[m], bfr[n], acc[m][n], 0, 0, 0);           \
        }                                                             \
    } while (0)

    // prologue: stage K-tile 0 into buf 0 (8 loads in flight)
    STAGE(0, 0);

    int cur = 0;
    for (int t = 0; t < NT; ++t) {
        if (t + 1 < NT) {
            STAGE(cur ^ 1, (t + 1) * 64);   // 16 in flight (t and t+1)
            // wait ONLY for tile t's 8 loads; t+1's 8 keep flying
            asm volatile("s_waitcnt vmcnt(8)" ::: "memory");
        } else {
            asm volatile("s_waitcnt vmcnt(0)" ::: "memory");
        }
        __builtin_amdgcn_s_barrier();       // all waves: buf cur fully staged
        asm volatile("" ::: "memory");      // fence: no ds_read hoist/sink
        COMPUTE(cur);                       // ds_read + MFMA (lgkm auto)
        asm volatile("" ::: "memory");      // keep ds_reads above the barrier
        __builtin_amdgcn_s_barrier();       // done reading cur; next iter may
        cur ^= 1;                           // overwrite it
    }

    // --- fused epilogue: cos -> sims -> exp -> row/col partial sums ---
    // C/D layout: col = lane&15, row = (lane>>4)*4 + r
    const int fcol  = lane & 15;
    const int frow0 = (lane >> 4) * 4;

    float rnj[4];
    #pragma unroll
    for (int n = 0; n < 4; ++n)
        rnj[n] = rn[bcol + wc * 64 + n * 16 + fcol];

    float colacc[4] = {0.f, 0.f, 0.f, 0.f};

    #pragma unroll
    for (int m = 0; m < 4; ++m) {
        #pragma unroll
        for (int r = 0; r < 4; ++r) {
            const int i = brow + wr * 64 + m * 16 + frow0 + r;
            const float lni = ln[i];
            float rowacc = 0.f;
            #pragma unroll
            for (int n = 0; n < 4; ++n) {
                const int j = bcol + wc * 64 + n * 16 + fcol;
                const float denom = fmaxf(lni * rnj[n], 1e-8f);
                const float v = acc[m][n][r] * 10.0f / denom;
                if (diagblk && i == j) diag[i] = v;
                const float e = __expf(v);
                if (i <= j) rowacc += e;
                if (i < j)  colacc[n] += e;
            }
            rowacc += __shfl_xor(rowacc, 1);
            rowacc += __shfl_xor(rowacc, 2);
            rowacc += __shfl_xor(rowacc, 4);
            rowacc += __shfl_xor(rowacc, 8);
            if (fcol == 0) atomicAdd(&rowsum[i], rowacc);
        }
    }
    #pragma unroll
    for (int n = 0; n < 4; ++n) {
        float c = colacc[n];
        c += __shfl_xor(c, 16);
        c += __shfl_xor(c, 32);
        if (lane < 16) {
            const int j = bcol + wc * 64 + n * 16 + fcol;
            atomicAdd(&rowsum[j], c);
        }
    }
#undef STAGE
#undef COMPUTE
}

// loss = mean_i( log(rowsum[i]) - diag[i] )
__global__ __launch_bounds__(1024) void final_loss_kernel(
        const float* __restrict__ rowsum, const float* __restrict__ diag,
        float* __restrict__ out) {
    float s = 0.f;
    for (int i = threadIdx.x; i < B_DIM; i += 1024)
        s += logf(rowsum[i]) - diag[i];
    __shared__ float red[16];
    float w = wave_reduce_sum(s);
    if ((threadIdx.x & 63) == 0) red[threadIdx.x >> 6] = w;
    __syncthreads();
    if (threadIdx.x == 0) {
        float tot = 0.f;
        #pragma unroll
        for (int k = 0; k < 16; ++k) tot += red[k];
        out[0] = tot / (float)B_DIM;
    }
}

extern "C" void kernel_launch(void* const* d_in, const int* in_sizes, int n_in,
                              void* d_out, int out_size, void* d_ws, size_t ws_size,
                              hipStream_t stream) {
    const float* L = (const float*)d_in[0];
    const float* R = (const float*)d_in[1];

    char* ws = (char*)d_ws;
    size_t o = 0;
    u16* Lbf   = (u16*)(ws + o);   o += (size_t)B_DIM * D_DIM * sizeof(u16);
    u16* Rbf   = (u16*)(ws + o);   o += (size_t)B_DIM * D_DIM * sizeof(u16);
    float* ln  = (float*)(ws + o); o += (size_t)B_DIM * sizeof(float);
    float* rn  = (float*)(ws + o); o += (size_t)B_DIM * sizeof(float);
    float* rs  = (float*)(ws + o); o += (size_t)B_DIM * sizeof(float);
    float* dg  = (float*)(ws + o); o += (size_t)B_DIM * sizeof(float);

    norm_convert_kernel<<<2 * B_DIM / 4, 256, 0, stream>>>(L, R, Lbf, Rbf, ln, rn, rs);

    const int nblocks = TT * (TT + 1) / 2;   // 528 upper-triangular tiles
    gemm_fused_kernel<<<nblocks, 256, 0, stream>>>(Lbf, Rbf, ln, rn, rs, dg);

    final_loss_kernel<<<1, 1024, 0, stream>>>(rs, dg, (float*)d_out);
}